// Round 9
// baseline (446.843 us; speedup 1.0000x reference)
//
#include <hip/hip_runtime.h>
#include <cstdint>
#include <cmath>

#define N_HEADS 16
#define I_DIM 128
#define H_DIM 128
#define B_SZ 16
#define T_SZ 512
#define G3 384           // 3*H
#define OUT_HN_OFFSET ((size_t)B_SZ * T_SZ * (N_HEADS * H_DIM)) // 16777216
#define CHUNK 16
#define NCHUNK (T_SZ / CHUNK) // 32
#define HPAD 160   // h2 parity stride in ushorts (320B -> disjoint banks)
#define GROWP 520  // gbuf row stride in floats (pad: quads' scatter rows -> distinct banks)

typedef __attribute__((ext_vector_type(8))) short bf16x8;
typedef __attribute__((ext_vector_type(4))) float f32x4;

static __device__ __forceinline__ unsigned short f2bf(float f) {
  unsigned int u = __float_as_uint(f);
  unsigned int r = (u + 0x7FFFu + ((u >> 16) & 1u)) >> 16; // RNE
  return (unsigned short)r;
}
static __device__ __forceinline__ float bf2f(unsigned short s) {
  return __uint_as_float((unsigned int)s << 16);
}
static __device__ __forceinline__ uint2 pack4(float4 v) {
  uint2 p;
  p.x = (unsigned int)f2bf(v.x) | ((unsigned int)f2bf(v.y) << 16);
  p.y = (unsigned int)f2bf(v.z) | ((unsigned int)f2bf(v.w) << 16);
  return p;
}
static __device__ __forceinline__ bf16x8 pack8(float4 a, float4 b) {
  union { uint2 u[2]; bf16x8 v; } r;
  r.u[0] = pack4(a);
  r.u[1] = pack4(b);
  return r.v;
}

// ---------------------------------------------------------------------------
// FUSED GRU kernel v2. One WG (256 thr = 4 waves) per (b,n); grid = 256.
//
// R8 post-mortem: fused passed (absmax 0.0078) but the serial chunk-top
// gates_x block cost ~300cy/step-equiv (dispatch 359 vs 294 scan-only).
// v2 makes gates_x (nearly) free:
//  * CHUNK 16: A-row = m16 = t-within-chunk, so ALL 16 MFMA D-rows are
//    valid (quads 0..3 scatter 4 rows each). The same 24 MFMAs/wave now
//    cover 16 steps; chunk-boundary vmcnt drains halve (1 per 16 steps).
//  * Interleave: step s<6 carries one gates_x colblock (4 MFMA + 4
//    ds_write into the OTHER gbuf). Static s (unrolled loop) keeps wxf[s]
//    register-resident. These issue into the step's idle MFMA slots and
//    hide under the update-VALU chain.
//  * gbuf rows padded to 520 floats: the 4 quads' scatter rows (stride
//    2080B) land on different banks.
// Per-element math identical to R8 (passed): n-gate keeps bhh_n inside the
// r-product; gates_x fp32 end-to-end.
// ---------------------------------------------------------------------------
__global__ __launch_bounds__(256, 1) void gru_fused_kernel(
    const float* __restrict__ x, const float* __restrict__ h0,
    const float* __restrict__ w_ih, const float* __restrict__ w_hh,
    const float* __restrict__ b_ih, const float* __restrict__ b_hh,
    float* __restrict__ out) {
  const int b = blockIdx.x >> 4;
  const int n = blockIdx.x & 15;
  const int tid = threadIdx.x;
  const int wave = tid >> 6;
  const int lane = tid & 63;
  const int m16 = lane & 15;
  const int quad = lane >> 4;

  __shared__ __align__(16) unsigned short h2[2][2][HPAD];  // [buf][hi|lo]
  __shared__ __align__(16) float gbuf[2][CHUNK][GROWP];    // ~66.5 KB

  // ---- W_hh B-fragments (proven mapping): wave w owns colblocks
  // {2w, 8+2w, 16+2w, 2w+1, 9+2w, 17+2w} = r0,z0,n0,r1,z1,n1 for its elems.
  bf16x8 wf[6][4];
  {
    const int cb0 = 2 * wave;
    const int cbs[6] = {cb0, 8 + cb0, 16 + cb0, cb0 + 1, 9 + cb0, 17 + cb0};
#pragma unroll
    for (int j = 0; j < 6; ++j) {
      const int g = cbs[j] * 16 + m16;
      const float4* wr = (const float4*)(w_hh + ((size_t)n * G3 + g) * H_DIM);
#pragma unroll
      for (int kt = 0; kt < 4; ++kt)
        wf[j][kt] = pack8(wr[kt * 8 + quad * 2], wr[kt * 8 + quad * 2 + 1]);
    }
  }

  // ---- W_ih B-fragments: wave owns gates_x colblocks wave*6+jj (jj 0..5).
  bf16x8 wxf[6][4];
#pragma unroll
  for (int jj = 0; jj < 6; ++jj) {
    const int g = (wave * 6 + jj) * 16 + m16;
    const float4* wr = (const float4*)(w_ih + ((size_t)n * G3 + g) * I_DIM);
#pragma unroll
    for (int kt = 0; kt < 4; ++kt)
      wxf[jj][kt] = pack8(wr[kt * 8 + quad * 2], wr[kt * 8 + quad * 2 + 1]);
  }

  const bool upd = quad < 2;                    // 128 updating lanes
  const int elem = wave * 32 + quad * 16 + m16; // h element owned (if upd)

  // Biases: r/z fuse (symmetric); n-gate keeps bhh_n inside the r-product.
  float bs_r = 0.f, bs_z = 0.f, bs_n = 0.f, bh_n = 0.f, h_old = 0.f;
  if (upd) {
    bs_r = b_ih[n * G3 + elem] + b_hh[n * G3 + elem];
    bs_z = b_ih[n * G3 + elem + 128] + b_hh[n * G3 + elem + 128];
    bs_n = b_ih[n * G3 + elem + 256]; // bih_n only
    bh_n = b_hh[n * G3 + elem + 256]; // stays inside r*( . )
    h_old = h0[(size_t)b * 2048 + n * H_DIM + elem];
    const unsigned short hh = f2bf(h_old);
    h2[0][0][elem] = hh;
    h2[0][1][elem] = f2bf(h_old - bf2f(hh));
  }

  // X A-frag source: lane (m16,quad) covers A-row m16 = t-within-chunk,
  // k-slice kt*32 + quad*8 .. +8 (two float4 per kt). All 16 rows real.
  const float* xrow_base = x + (size_t)b * T_SZ * 2048 + n * I_DIM +
                           (size_t)m16 * 2048 + quad * 8;

  float4 pf[8];   // X of chunk (c+1) in flight / resident
  bf16x8 af[4];   // packed A-frags of the chunk currently being produced

#define LOAD_X_CHUNK(c)                                                       \
  {                                                                           \
    const float* xr = xrow_base + (size_t)(c) * CHUNK * 2048;                 \
    _Pragma("unroll") for (int kt = 0; kt < 4; ++kt) {                        \
      pf[kt * 2] = *(const float4*)(xr + kt * 32);                            \
      pf[kt * 2 + 1] = *(const float4*)(xr + kt * 32 + 4);                    \
    }                                                                         \
  }

#define PACK_AF()                                                             \
  {                                                                           \
    _Pragma("unroll") for (int kt = 0; kt < 4; ++kt)                          \
        af[kt] = pack8(pf[kt * 2], pf[kt * 2 + 1]);                           \
  }

  // One gates_x colblock jj (static): 4 MFMA + 4 scatter writes, all lanes.
#define GATES_X_GROUP(jj, gdst)                                               \
  {                                                                           \
    f32x4 a = {0.f, 0.f, 0.f, 0.f};                                           \
    a = __builtin_amdgcn_mfma_f32_16x16x32_bf16(af[0], wxf[jj][0], a, 0, 0, 0);\
    a = __builtin_amdgcn_mfma_f32_16x16x32_bf16(af[1], wxf[jj][1], a, 0, 0, 0);\
    a = __builtin_amdgcn_mfma_f32_16x16x32_bf16(af[2], wxf[jj][2], a, 0, 0, 0);\
    a = __builtin_amdgcn_mfma_f32_16x16x32_bf16(af[3], wxf[jj][3], a, 0, 0, 0);\
    const int g_ = (wave * 6 + (jj)) * 16 + m16;                              \
    const int e4_ = (g_ & 127) * 4 + (g_ >> 7);                               \
    (gdst)[(quad * 4 + 0) * GROWP + e4_] = a[0];                              \
    (gdst)[(quad * 4 + 1) * GROWP + e4_] = a[1];                              \
    (gdst)[(quad * 4 + 2) * GROWP + e4_] = a[2];                              \
    (gdst)[(quad * 4 + 3) * GROWP + e4_] = a[3];                              \
  }

  // ---- prologue: chunk 0's gates_x staged (serial, once); X(1) in pf ----
  LOAD_X_CHUNK(0);
  PACK_AF();
  GATES_X_GROUP(0, &gbuf[0][0][0]);
  GATES_X_GROUP(1, &gbuf[0][0][0]);
  GATES_X_GROUP(2, &gbuf[0][0][0]);
  GATES_X_GROUP(3, &gbuf[0][0][0]);
  GATES_X_GROUP(4, &gbuf[0][0][0]);
  GATES_X_GROUP(5, &gbuf[0][0][0]);
  LOAD_X_CHUNK(1);
  __syncthreads();

  float* out_base = out + (size_t)b * T_SZ * 2048 + n * H_DIM;
  float oreg[CHUNK];

  for (int c = 0; c < NCHUNK; ++c) {
    const int gb = c & 1;

    // Chunk top (window shared with prev chunk's out stores -> ONE vmcnt
    // drain at step 0's barrier): pack af = X(c+1); issue X(c+2) loads.
    if (c + 1 < NCHUNK) {
      PACK_AF();
      if (c + 2 < NCHUNK) LOAD_X_CHUNK(c + 2);
    }

#pragma unroll
    for (int s = 0; s < CHUNK; ++s) {
      const int rb = s & 1; // chunk length even -> parity restarts at 0
      const int wb = rb ^ 1;

      // gates_x for THIS step: ONE ds_read_b128 -> {r, z, n, pad} fp32.
      float gxr = 0.f, gxz = 0.f, gxn = 0.f;
      if (upd) {
        const f32x4 g4 = *(const f32x4*)&gbuf[gb][s][elem * 4];
        gxr = g4[0];
        gxz = g4[1];
        gxn = g4[2];
      }

      // h A-fragments (hi for even m16 rows, lo for odd; HPAD bank-split).
      const unsigned short* hsrc = &h2[rb][m16 & 1][0];
      const bf16x8 av0 = *(const bf16x8*)&hsrc[0 * 32 + quad * 8];
      const bf16x8 av1 = *(const bf16x8*)&hsrc[1 * 32 + quad * 8];
      const bf16x8 av2 = *(const bf16x8*)&hsrc[2 * 32 + quad * 8];
      const bf16x8 av3 = *(const bf16x8*)&hsrc[3 * 32 + quad * 8];

      f32x4 acc[6];
#pragma unroll
      for (int j = 0; j < 6; ++j) acc[j] = (f32x4){0.f, 0.f, 0.f, 0.f};
#pragma unroll
      for (int j = 0; j < 6; ++j)
        acc[j] = __builtin_amdgcn_mfma_f32_16x16x32_bf16(av0, wf[j][0], acc[j],
                                                         0, 0, 0);
#pragma unroll
      for (int j = 0; j < 6; ++j)
        acc[j] = __builtin_amdgcn_mfma_f32_16x16x32_bf16(av1, wf[j][1], acc[j],
                                                         0, 0, 0);
#pragma unroll
      for (int j = 0; j < 6; ++j)
        acc[j] = __builtin_amdgcn_mfma_f32_16x16x32_bf16(av2, wf[j][2], acc[j],
                                                         0, 0, 0);
#pragma unroll
      for (int j = 0; j < 6; ++j)
        acc[j] = __builtin_amdgcn_mfma_f32_16x16x32_bf16(av3, wf[j][3], acc[j],
                                                         0, 0, 0);

      // Interleaved gates_x for chunk c+1: one colblock per step (s<6).
      // Independent MFMAs fill this step's idle matrix-pipe slots; the
      // ds_writes land in the OTHER gbuf (read 16+ barriers later).
      if (s < 6 && c + 1 < NCHUNK) {
        GATES_X_GROUP(s, &gbuf[gb ^ 1][0][0]);
      }

      if (upd) {
        // D[0] = W.h_hi, D[1] = W.h_lo (rows 0,1 of each quad's 4).
        const float ghr =
            (quad ? acc[3][0] + acc[3][1] : acc[0][0] + acc[0][1]);
        const float ghz =
            (quad ? acc[4][0] + acc[4][1] : acc[1][0] + acc[1][1]);
        const float ghn0 =
            (quad ? acc[5][0] + acc[5][1] : acc[2][0] + acc[2][1]);
        const float r = 1.f / (1.f + __expf(-(gxr + ghr + bs_r)));
        const float z = 1.f / (1.f + __expf(-(gxz + ghz + bs_z)));
        // Reference ordering: n = tanh(gx_n + bih_n + r*(Wh_n + bhh_n)).
        const float targ = gxn + bs_n + r * (ghn0 + bh_n);
        const float rt = 1.f / (1.f + __expf(-2.f * targ)); // sigmoid(2x)
        const float nn = 2.f * rt - 1.f;                    // tanh(targ)
        const float hn = (1.f - z) * nn + z * h_old;
        const unsigned short hh = f2bf(hn);
        h2[wb][0][elem] = hh;
        h2[wb][1][elem] = f2bf(hn - bf2f(hh));
        h_old = hn;
        oreg[s] = hn;
      }
      __syncthreads();
    }

    // Batched out stores; drained (with the X loads issued at next chunk
    // top) at next chunk's step-0 barrier — one drain per 16 steps.
    if (upd) {
#pragma unroll
      for (int s = 0; s < CHUNK; ++s)
        out_base[(size_t)(c * CHUNK + s) * 2048 + elem] = oreg[s];
    }
  }

  if (upd) {
    out[OUT_HN_OFFSET + (size_t)b * 2048 + n * H_DIM + elem] = h_old;
  }
}

extern "C" void kernel_launch(void* const* d_in, const int* in_sizes, int n_in,
                              void* d_out, int out_size, void* d_ws,
                              size_t ws_size, hipStream_t stream) {
  const float* x    = (const float*)d_in[0]; // [B, T, N*I]
  const float* h0   = (const float*)d_in[1]; // [1, B, N*H]
  const float* w_ih = (const float*)d_in[2]; // [N, 3H, I]
  const float* w_hh = (const float*)d_in[3]; // [N, 3H, H]
  const float* b_ih = (const float*)d_in[4]; // [N, 3H]
  const float* b_hh = (const float*)d_in[5]; // [N, 3H]
  float* out = (float*)d_out;
  (void)d_ws; // fused kernel: no gates workspace needed

  gru_fused_kernel<<<256, 256, 0, stream>>>(x, h0, w_ih, w_hh, b_ih, b_hh,
                                            out);
}